// Round 2
// baseline (315.773 us; speedup 1.0000x reference)
//
#include <hip/hip_runtime.h>
#include <hip/hip_bf16.h>
#include <cstdint>
#include <cstddef>

// Problem constants: B=1, L=4096, DM=1024, NH=16, DH=64, w=512, C=8
#define L_ 4096
#define DM_ 1024
#define NH_ 16
#define DH_ 64
#define W_ 512
#define C_ 8
#define W3_ 1536
#define NROWS_ 65536

typedef __attribute__((ext_vector_type(8))) short short8;
typedef __attribute__((ext_vector_type(4))) float f32x4;

__device__ __forceinline__ void async16(const void* g, void* l) {
    __builtin_amdgcn_global_load_lds(
        (const __attribute__((address_space(1))) unsigned int*)g,
        (__attribute__((address_space(3))) unsigned int*)l, 16, 0, 0);
}

#if __has_builtin(__builtin_amdgcn_exp2f)
#define FEXP2(x) __builtin_amdgcn_exp2f(x)
#else
#define FEXP2(x) exp2f(x)
#endif

// ---------------------------------------------------------------------------
// Input-dtype detector (fp32 vs bf16).
// ---------------------------------------------------------------------------
__device__ __forceinline__ int nanhit(unsigned u) {
    return (((u & 0x7F80u) == 0x7F80u) | (((u >> 16) & 0x7F80u) == 0x7F80u));
}
__global__ __launch_bounds__(256) void detect_kernel(const uint4* __restrict__ q,
                                                     int* __restrict__ flag) {
    __shared__ int s;
    if (threadIdx.x == 0) s = 0;
    __syncthreads();
    int hit = 0;
#pragma unroll
    for (int r = 0; r < 8; ++r) {
        uint4 v = q[threadIdx.x + 256 * r];
        hit |= nanhit(v.x) | nanhit(v.y) | nanhit(v.z) | nanhit(v.w);
    }
    if (__any(hit)) { if ((threadIdx.x & 63) == 0) atomicOr(&s, 1); }
    __syncthreads();
    if (threadIdx.x == 0) flag[0] = s;
}

__device__ __forceinline__ float ldf(const void* X, size_t i, int f32) {
    return f32 ? ((const float*)X)[i] : __bfloat162float(((const __hip_bfloat16*)X)[i]);
}

// ---------------------------------------------------------------------------
// Megaprep (one dispatch): q convert (4096 blocks), Wq^T (256), Wc^T (256),
// Wkv^T (32), kvred build (1536): rows 0..511 = sum of 8 chunks of kv,
// 512..1023 = first chunk, 1024..1535 = last chunk (all bf16).
// ---------------------------------------------------------------------------
__global__ __launch_bounds__(256) void megaprep(const void* __restrict__ q,
                                                const void* __restrict__ kv,
                                                const void* __restrict__ Wq,
                                                const void* __restrict__ Wkv,
                                                const void* __restrict__ Wc,
                                                __hip_bfloat16* __restrict__ qbuf,
                                                __hip_bfloat16* __restrict__ WqT,
                                                __hip_bfloat16* __restrict__ WkvT,
                                                __hip_bfloat16* __restrict__ WcT,
                                                __hip_bfloat16* __restrict__ kvred,
                                                const int* __restrict__ flag) {
    __shared__ float t[64][65];
    const int b = blockIdx.x;
    const int f32 = flag[0];
    const int tid = threadIdx.x;

    if (b < 4096) {
        int i = (b * 256 + tid) * 4;
        if (f32) {
            float4 v = *(const float4*)((const float*)q + i);
            __hip_bfloat162 tmp[2] = {__float22bfloat162_rn({v.x, v.y}),
                                      __float22bfloat162_rn({v.z, v.w})};
            *(short4*)((short*)qbuf + i) = *(const short4*)tmp;
        } else {
            *(short4*)((short*)qbuf + i) = *(const short4*)((const short*)q + i);
        }
    } else if (b < 4640) {
        const void* W;
        __hip_bfloat16* WT;
        int K = 1024, N, n0, k0;
        if (b < 4352) {
            int bx = b - 4096; W = Wq; WT = WqT; N = 1024;
            n0 = (bx & 15) * 64; k0 = (bx >> 4) * 64;
        } else if (b < 4608) {
            int bx = b - 4352; W = Wc; WT = WcT; N = 1024;
            n0 = (bx & 15) * 64; k0 = (bx >> 4) * 64;
        } else {
            int bx = b - 4608; W = Wkv; WT = WkvT; N = 128;
            n0 = (bx & 1) * 64; k0 = (bx >> 1) * 64;
        }
        const int tx = tid & 63;
        const int ty = tid >> 6;
#pragma unroll
        for (int r = 0; r < 16; ++r) {
            int k = ty + r * 4;
            t[k][tx] = ldf(W, (size_t)(k0 + k) * N + n0 + tx, f32);
        }
        __syncthreads();
#pragma unroll
        for (int r = 0; r < 16; ++r) {
            int n = ty + r * 4;
            WT[(size_t)(n0 + n) * K + k0 + tx] = __float2bfloat16(t[tx][n]);
        }
    } else {
        int y2 = b - 4640;          // 0..1535
        int c = tid * 4;
        float a0 = 0.f, a1 = 0.f, a2 = 0.f, a3 = 0.f;
        if (y2 < 512) {
#pragma unroll
            for (int z = 0; z < C_; ++z) {
                size_t base = (size_t)(z * W_ + y2) * 1024 + c;
                a0 += ldf(kv, base + 0, f32);
                a1 += ldf(kv, base + 1, f32);
                a2 += ldf(kv, base + 2, f32);
                a3 += ldf(kv, base + 3, f32);
            }
        } else {
            int row = (y2 < 1024) ? (y2 - 512) : (3584 + y2 - 1024);
            size_t base = (size_t)row * 1024 + c;
            a0 = ldf(kv, base + 0, f32);
            a1 = ldf(kv, base + 1, f32);
            a2 = ldf(kv, base + 2, f32);
            a3 = ldf(kv, base + 3, f32);
        }
        __hip_bfloat162 tmp[2] = {__float22bfloat162_rn({a0, a1}),
                                  __float22bfloat162_rn({a2, a3})};
        *(short4*)((short*)kvred + (size_t)y2 * 1024 + c) = *(const short4*)tmp;
    }
}

// ---------------------------------------------------------------------------
// MFMA GEMM: C[M,N] = alpha * A[M,K] @ BT[N,K]^T, bf16 in, fp32 accum.
// 128x64 tile, BK=64 (two BK=32 sub-tiles). swz=1: XCD swizzle mapping.
// cMode: 0 = follow flag (fp32 if flag else bf16), 1 = fp32, 2 = bf16.
// Dual-problem dispatch: blocks [0, p0.nblocks) run p0, the rest run p1.
// ---------------------------------------------------------------------------
struct GemmP {
    const __hip_bfloat16* A;
    const __hip_bfloat16* BT;
    void* C;
    int M, N, K;
    float alpha;
    int cMode;
    int ntiles;   // N / 64
    int swz;
    int nblocks;
};

__global__ __launch_bounds__(256) void gemm_bt_mfma(GemmP p0, GemmP p1,
                                                    const int* __restrict__ flag) {
    __shared__ __hip_bfloat16 Asl[2][128 * 32];
    __shared__ __hip_bfloat16 Bsl[2][64 * 32];

    GemmP p;
    int bid;
    if ((int)blockIdx.x < p0.nblocks) { p = p0; bid = blockIdx.x; }
    else { p = p1; bid = (int)blockIdx.x - p0.nblocks; }

    int mt, nt;
    if (!p.swz) { mt = bid / p.ntiles; nt = bid % p.ntiles; }
    else {
        int g = bid / (8 * p.ntiles);
        int rem = bid % (8 * p.ntiles);
        mt = g * 8 + (rem & 7);
        nt = rem >> 3;
    }
    const int m0 = mt * 128;
    const int n0 = nt * 64;
    const int K = p.K;
    const int N = p.N;

    const int tid = threadIdx.x;
    const int lane = tid & 63;
    const int wv = tid >> 6;
    const int wm = wv >> 1;
    const int wn = wv & 1;
    const int col = lane & 15;
    const int quad = lane >> 4;

    const int srow = lane >> 2;
    const int scol = (lane & 3) * 8;
    const __hip_bfloat16* Ag = p.A + (size_t)m0 * K;
    const __hip_bfloat16* Bg = p.BT + (size_t)n0 * K;

    f32x4 acc[4][2] = {};

    for (int k0 = 0; k0 < K; k0 += 64) {
#pragma unroll
        for (int h = 0; h < 2; ++h) {
            int arow = wv * 32 + h * 16 + srow;
#pragma unroll
            for (int kc = 0; kc < 2; ++kc)
                async16(Ag + (size_t)arow * K + k0 + kc * 32 + scol,
                        &Asl[kc][arow * 32 + scol]);
        }
        {
            int brow = wv * 16 + srow;
#pragma unroll
            for (int kc = 0; kc < 2; ++kc)
                async16(Bg + (size_t)brow * K + k0 + kc * 32 + scol,
                        &Bsl[kc][brow * 32 + scol]);
        }
        __syncthreads();

#pragma unroll
        for (int kc = 0; kc < 2; ++kc) {
            short8 af[4], bfr[2];
#pragma unroll
            for (int i = 0; i < 4; ++i)
                af[i] = *(const short8*)(&Asl[kc][(wm * 64 + i * 16 + col) * 32 + quad * 8]);
#pragma unroll
            for (int j = 0; j < 2; ++j)
                bfr[j] = *(const short8*)(&Bsl[kc][(wn * 32 + j * 16 + col) * 32 + quad * 8]);
#pragma unroll
            for (int am = 0; am < 4; ++am)
#pragma unroll
                for (int bn = 0; bn < 2; ++bn)
                    acc[am][bn] = __builtin_amdgcn_mfma_f32_16x16x32_bf16(af[am], bfr[bn], acc[am][bn], 0, 0, 0);
        }
        __syncthreads();
    }

    int cF = (p.cMode == 1) ? 1 : ((p.cMode == 2) ? 0 : flag[0]);
#pragma unroll
    for (int am = 0; am < 4; ++am)
#pragma unroll
        for (int bn = 0; bn < 2; ++bn)
#pragma unroll
            for (int r = 0; r < 4; ++r) {
                size_t ci = (size_t)(m0 + wm * 64 + am * 16 + quad * 4 + r) * N
                            + n0 + wn * 32 + bn * 16 + col;
                float v = acc[am][bn][r] * p.alpha;
                if (cF) ((float*)p.C)[ci] = v;
                else ((__hip_bfloat16*)p.C)[ci] = __float2bfloat16(v);
            }
}

// ---------------------------------------------------------------------------
// Combine kvp_red [1536][128] fp32 -> bf16 Kb [1536][64] and Vt [64][1536]
// with the R8 key permutation within 64-groups: p = ((i&15)<<2) | (i>>4),
// matching attn P LDS layout (pos = col*4 + f).
// ---------------------------------------------------------------------------
__global__ __launch_bounds__(256) void sums_kernel(const float* __restrict__ kvp_red,
                                                   __hip_bfloat16* __restrict__ Kb,
                                                   __hip_bfloat16* __restrict__ Vt) {
    int t = blockIdx.x * 256 + threadIdx.x;
    int d = t & 63;
    int y = t >> 6;

    float kc = kvp_red[(size_t)y * 128 + d];
    float kf = kvp_red[(size_t)(512 + y) * 128 + d];
    float kl = kvp_red[(size_t)(1024 + y) * 128 + d];
    float vc = kvp_red[(size_t)y * 128 + 64 + d];
    float vf = kvp_red[(size_t)(512 + y) * 128 + 64 + d];
    float vl = kvp_red[(size_t)(1024 + y) * 128 + 64 + d];

    float kvals[3] = {kc - kl, kc, kc - kf};
    float vvals[3] = {vc - vl, vc, vc - vf};
#pragma unroll
    for (int e = 0; e < 3; ++e) {
        int key = e * W_ + y;
        Kb[(size_t)key * 64 + d] = __float2bfloat16(kvals[e]);
        int g = key >> 6;
        int i = key & 63;
        int p = ((i & 15) << 2) | (i >> 4);
        Vt[(size_t)d * W3_ + g * 64 + p] = __float2bfloat16(vvals[e]);
    }
}

// ---------------------------------------------------------------------------
// Flash MFMA attention — Round 2: q-row-split. Each wave owns 16 q-rows and
// iterates ALL 1536 keys (24 t-iters of 64). vs the old key-split (64 rows x
// 384 keys/wave):
//  - persistent regs 112 -> ~28 (qf 8, O 16, lrow 4)  => launch_bounds(256,4)
//  - P LDS 37.9KB -> 9.2KB/block (16 rows/wave)        => 4+ blocks/CU
//  - cross-wave LDS reduction epilogue deleted (lrow/O complete per wave)
// K/V loads amplified 4x but Kb+Vt = 384KB is L2-resident; 4 waves/block walk
// tiles in the same order -> L1 broadcast. Fragment indexing identical
// (rg -> wv, kt = t*64). T5 setprio around MFMA clusters kept.
// ---------------------------------------------------------------------------
#define PSTRIDE 72
__global__ __launch_bounds__(256, 4) void attn_kernel(const __hip_bfloat16* __restrict__ qb,
                                                      const __hip_bfloat16* __restrict__ Kb,
                                                      const __hip_bfloat16* __restrict__ Vt,
                                                      __hip_bfloat16* __restrict__ ctx) {
    __shared__ __align__(16) __hip_bfloat16 psm[4][16 * PSTRIDE];

    const int tid = threadIdx.x;
    const int lane = tid & 63;
    const int wv = tid >> 6;
    const int m0 = blockIdx.x * 64 + wv * 16;   // this wave's 16 q-rows
    const int col = lane & 15;
    const int quad = lane >> 4;
    __hip_bfloat16* pw = psm[wv];

    short8 qf0, qf1;
    {
        const __hip_bfloat16* qp = qb + (size_t)(m0 + col) * 64 + quad * 8;
        qf0 = *(const short8*)(qp);
        qf1 = *(const short8*)(qp + 32);
    }

    f32x4 O[4] = {};
    float lrow[4] = {};

    for (int t = 0; t < 24; ++t) {
        const int kt = t * 64;

        short8 kb0[4], kb1[4];
#pragma unroll
        for (int f = 0; f < 4; ++f) {
            const __hip_bfloat16* kp = Kb + (size_t)(kt + f * 16 + col) * 64 + quad * 8;
            kb0[f] = *(const short8*)(kp);
            kb1[f] = *(const short8*)(kp + 32);
        }

        f32x4 S[4];
        __builtin_amdgcn_s_setprio(1);
#pragma unroll
        for (int f = 0; f < 4; ++f) {
            f32x4 s = {};
            s = __builtin_amdgcn_mfma_f32_16x16x32_bf16(qf0, kb0[f], s, 0, 0, 0);
            s = __builtin_amdgcn_mfma_f32_16x16x32_bf16(qf1, kb1[f], s, 0, 0, 0);
            S[f] = s;
        }
        __builtin_amdgcn_s_setprio(0);
#pragma unroll
        for (int f = 0; f < 4; ++f)
#pragma unroll
            for (int r = 0; r < 4; ++r) S[f][r] = FEXP2(S[f][r]);
#pragma unroll
        for (int r = 0; r < 4; ++r)
            lrow[r] += (S[0][r] + S[1][r]) + (S[2][r] + S[3][r]);
#pragma unroll
        for (int r = 0; r < 4; ++r) {
            __hip_bfloat162 p01 = __float22bfloat162_rn({S[0][r], S[1][r]});
            __hip_bfloat162 p23 = __float22bfloat162_rn({S[2][r], S[3][r]});
            short4 t4;
            *(__hip_bfloat162*)(&t4.x) = p01;
            *(__hip_bfloat162*)(&t4.z) = p23;
            *(short4*)(pw + (quad * 4 + r) * PSTRIDE + col * 4) = t4;
        }

        short8 vb0[4], vb1[4];
#pragma unroll
        for (int f = 0; f < 4; ++f) {
            const __hip_bfloat16* vp = Vt + (size_t)(f * 16 + col) * W3_ + kt + quad * 8;
            vb0[f] = *(const short8*)(vp);
            vb1[f] = *(const short8*)(vp + 32);
        }

        short8 a0 = *(const short8*)(pw + col * PSTRIDE + quad * 8);
        short8 a1 = *(const short8*)(pw + col * PSTRIDE + 32 + quad * 8);
        __builtin_amdgcn_s_setprio(1);
#pragma unroll
        for (int f = 0; f < 4; ++f) {
            O[f] = __builtin_amdgcn_mfma_f32_16x16x32_bf16(a0, vb0[f], O[f], 0, 0, 0);
            O[f] = __builtin_amdgcn_mfma_f32_16x16x32_bf16(a1, vb1[f], O[f], 0, 0, 0);
        }
        __builtin_amdgcn_s_setprio(0);
    }

    // Sum lrow across the 16 cols of each quad-group (keys mod 16).
#pragma unroll
    for (int msk = 1; msk <= 8; msk <<= 1)
#pragma unroll
        for (int r = 0; r < 4; ++r) lrow[r] += __shfl_xor(lrow[r], msk, 64);

    // Direct epilogue: O[f][r] is ctx[row = m0 + quad*4 + r][dh = f*16 + col].
#pragma unroll
    for (int r = 0; r < 4; ++r) {
        float inv = 1.f / lrow[r];
#pragma unroll
        for (int f = 0; f < 4; ++f)
            ctx[(size_t)(m0 + quad * 4 + r) * 64 + f * 16 + col] =
                __float2bfloat16(O[f][r] * inv);
    }
}

// ---------------------------------------------------------------------------
// Launch
// ---------------------------------------------------------------------------
extern "C" void kernel_launch(void* const* d_in, const int* in_sizes, int n_in,
                              void* d_out, int out_size, void* d_ws, size_t ws_size,
                              hipStream_t stream) {
    const void* q   = d_in[0];
    const void* kv  = d_in[1];
    const void* Wq  = d_in[2];
    const void* Wkv = d_in[3];
    const void* Wc  = d_in[4];

    char* ws = (char*)d_ws;
    size_t off = 0;
    int* flag = (int*)(ws + off); off += 1024;
    __hip_bfloat16* qbuf   = (__hip_bfloat16*)(ws + off); off += (size_t)L_ * DM_ * 2;     // 8 MB
    __hip_bfloat16* WqT    = (__hip_bfloat16*)(ws + off); off += (size_t)DM_ * DM_ * 2;    // 2 MB
    __hip_bfloat16* WkvT   = (__hip_bfloat16*)(ws + off); off += (size_t)128 * DM_ * 2;    // 256 KB
    __hip_bfloat16* WcT    = (__hip_bfloat16*)(ws + off); off += (size_t)DM_ * DM_ * 2;    // 2 MB
    __hip_bfloat16* qb     = (__hip_bfloat16*)(ws + off); off += (size_t)L_ * DM_ * 2;     // 8 MB
    __hip_bfloat16* kvred  = (__hip_bfloat16*)(ws + off); off += (size_t)1536 * 1024 * 2;  // 3 MB
    float*          kvpred = (float*)(ws + off);          off += (size_t)1536 * 128 * 4;   // 768 KB
    __hip_bfloat16* Kb     = (__hip_bfloat16*)(ws + off); off += (size_t)W3_ * 64 * 2;     // 192 KB
    __hip_bfloat16* Vt     = (__hip_bfloat16*)(ws + off); off += (size_t)64 * W3_ * 2;     // 192 KB
    __hip_bfloat16* ctxb   = (__hip_bfloat16*)(ws + off);                                  // 8 MB

    detect_kernel<<<1, 256, 0, stream>>>((const uint4*)q, flag);

    megaprep<<<6176, 256, 0, stream>>>(q, kv, Wq, Wkv, Wc,
                                       qbuf, WqT, WkvT, WcT, kvred, flag);

    // Merged dispatch: qb = (q @ Wq) * (1/8)*log2(e), bf16 (512 blocks) PLUS
    // kvp_red = kvred @ Wkv, fp32 (24 blocks riding on idle CUs).
    {
        GemmP pq{qbuf, WqT, (void*)qb, L_, DM_, DM_,
                 0.125f * 1.44269504f, 2, 16, 1, 512};
        GemmP pk{kvred, WkvT, (void*)kvpred, 1536, 128, DM_,
                 1.0f, 1, 2, 0, 24};
        gemm_bt_mfma<<<536, 256, 0, stream>>>(pq, pk, flag);
    }
    sums_kernel<<<128, 256, 0, stream>>>(kvpred, Kb, Vt);
    attn_kernel<<<dim3(NROWS_ / 64), 256, 0, stream>>>(qb, Kb, Vt, ctxb);
    // out = ctx @ Wc, dtype per flag
    {
        GemmP pc{ctxb, WcT, d_out, L_, DM_, DM_, 1.0f, 0, 16, 1, 512};
        GemmP pnull{};
        pnull.nblocks = 0;
        gemm_bt_mfma<<<512, 256, 0, stream>>>(pc, pnull, flag);
    }
}

// Round 3
// 188.451 us; speedup vs baseline: 1.6756x; 1.6756x over previous
//
#include <hip/hip_runtime.h>
#include <hip/hip_bf16.h>
#include <cstdint>
#include <cstddef>

// Problem constants: B=1, L=4096, DM=1024, NH=16, DH=64, w=512, C=8
#define L_ 4096
#define DM_ 1024
#define NH_ 16
#define DH_ 64
#define W_ 512
#define C_ 8
#define W3_ 1536
#define NROWS_ 65536

typedef __attribute__((ext_vector_type(8))) short short8;
typedef __attribute__((ext_vector_type(4))) float f32x4;

__device__ __forceinline__ void async16(const void* g, void* l) {
    __builtin_amdgcn_global_load_lds(
        (const __attribute__((address_space(1))) unsigned int*)g,
        (__attribute__((address_space(3))) unsigned int*)l, 16, 0, 0);
}

#if __has_builtin(__builtin_amdgcn_exp2f)
#define FEXP2(x) __builtin_amdgcn_exp2f(x)
#else
#define FEXP2(x) exp2f(x)
#endif

// ---------------------------------------------------------------------------
// Input-dtype detector (fp32 vs bf16).
// ---------------------------------------------------------------------------
__device__ __forceinline__ int nanhit(unsigned u) {
    return (((u & 0x7F80u) == 0x7F80u) | (((u >> 16) & 0x7F80u) == 0x7F80u));
}
__global__ __launch_bounds__(256) void detect_kernel(const uint4* __restrict__ q,
                                                     int* __restrict__ flag) {
    __shared__ int s;
    if (threadIdx.x == 0) s = 0;
    __syncthreads();
    int hit = 0;
#pragma unroll
    for (int r = 0; r < 8; ++r) {
        uint4 v = q[threadIdx.x + 256 * r];
        hit |= nanhit(v.x) | nanhit(v.y) | nanhit(v.z) | nanhit(v.w);
    }
    if (__any(hit)) { if ((threadIdx.x & 63) == 0) atomicOr(&s, 1); }
    __syncthreads();
    if (threadIdx.x == 0) flag[0] = s;
}

__device__ __forceinline__ float ldf(const void* X, size_t i, int f32) {
    return f32 ? ((const float*)X)[i] : __bfloat162float(((const __hip_bfloat16*)X)[i]);
}

// ---------------------------------------------------------------------------
// Megaprep (one dispatch): q convert (4096 blocks), Wq^T (256), Wc^T (256),
// Wkv^T (32), kvred build (1536): rows 0..511 = sum of 8 chunks of kv,
// 512..1023 = first chunk, 1024..1535 = last chunk (all bf16).
// ---------------------------------------------------------------------------
__global__ __launch_bounds__(256) void megaprep(const void* __restrict__ q,
                                                const void* __restrict__ kv,
                                                const void* __restrict__ Wq,
                                                const void* __restrict__ Wkv,
                                                const void* __restrict__ Wc,
                                                __hip_bfloat16* __restrict__ qbuf,
                                                __hip_bfloat16* __restrict__ WqT,
                                                __hip_bfloat16* __restrict__ WkvT,
                                                __hip_bfloat16* __restrict__ WcT,
                                                __hip_bfloat16* __restrict__ kvred,
                                                const int* __restrict__ flag) {
    __shared__ float t[64][65];
    const int b = blockIdx.x;
    const int f32 = flag[0];
    const int tid = threadIdx.x;

    if (b < 4096) {
        int i = (b * 256 + tid) * 4;
        if (f32) {
            float4 v = *(const float4*)((const float*)q + i);
            __hip_bfloat162 tmp[2] = {__float22bfloat162_rn({v.x, v.y}),
                                      __float22bfloat162_rn({v.z, v.w})};
            *(short4*)((short*)qbuf + i) = *(const short4*)tmp;
        } else {
            *(short4*)((short*)qbuf + i) = *(const short4*)((const short*)q + i);
        }
    } else if (b < 4640) {
        const void* W;
        __hip_bfloat16* WT;
        int K = 1024, N, n0, k0;
        if (b < 4352) {
            int bx = b - 4096; W = Wq; WT = WqT; N = 1024;
            n0 = (bx & 15) * 64; k0 = (bx >> 4) * 64;
        } else if (b < 4608) {
            int bx = b - 4352; W = Wc; WT = WcT; N = 1024;
            n0 = (bx & 15) * 64; k0 = (bx >> 4) * 64;
        } else {
            int bx = b - 4608; W = Wkv; WT = WkvT; N = 128;
            n0 = (bx & 1) * 64; k0 = (bx >> 1) * 64;
        }
        const int tx = tid & 63;
        const int ty = tid >> 6;
#pragma unroll
        for (int r = 0; r < 16; ++r) {
            int k = ty + r * 4;
            t[k][tx] = ldf(W, (size_t)(k0 + k) * N + n0 + tx, f32);
        }
        __syncthreads();
#pragma unroll
        for (int r = 0; r < 16; ++r) {
            int n = ty + r * 4;
            WT[(size_t)(n0 + n) * K + k0 + tx] = __float2bfloat16(t[tx][n]);
        }
    } else {
        int y2 = b - 4640;          // 0..1535
        int c = tid * 4;
        float a0 = 0.f, a1 = 0.f, a2 = 0.f, a3 = 0.f;
        if (y2 < 512) {
#pragma unroll
            for (int z = 0; z < C_; ++z) {
                size_t base = (size_t)(z * W_ + y2) * 1024 + c;
                a0 += ldf(kv, base + 0, f32);
                a1 += ldf(kv, base + 1, f32);
                a2 += ldf(kv, base + 2, f32);
                a3 += ldf(kv, base + 3, f32);
            }
        } else {
            int row = (y2 < 1024) ? (y2 - 512) : (3584 + y2 - 1024);
            size_t base = (size_t)row * 1024 + c;
            a0 = ldf(kv, base + 0, f32);
            a1 = ldf(kv, base + 1, f32);
            a2 = ldf(kv, base + 2, f32);
            a3 = ldf(kv, base + 3, f32);
        }
        __hip_bfloat162 tmp[2] = {__float22bfloat162_rn({a0, a1}),
                                  __float22bfloat162_rn({a2, a3})};
        *(short4*)((short*)kvred + (size_t)y2 * 1024 + c) = *(const short4*)tmp;
    }
}

// ---------------------------------------------------------------------------
// MFMA GEMM: C[M,N] = alpha * A[M,K] @ BT[N,K]^T, bf16 in, fp32 accum.
// 128x64 tile, BK=64 (two BK=32 sub-tiles). swz=1: XCD swizzle mapping.
// cMode: 0 = follow flag (fp32 if flag else bf16), 1 = fp32, 2 = bf16.
// Dual-problem dispatch: blocks [0, p0.nblocks) run p0, the rest run p1.
// ---------------------------------------------------------------------------
struct GemmP {
    const __hip_bfloat16* A;
    const __hip_bfloat16* BT;
    void* C;
    int M, N, K;
    float alpha;
    int cMode;
    int ntiles;   // N / 64
    int swz;
    int nblocks;
};

__global__ __launch_bounds__(256) void gemm_bt_mfma(GemmP p0, GemmP p1,
                                                    const int* __restrict__ flag) {
    __shared__ __hip_bfloat16 Asl[2][128 * 32];
    __shared__ __hip_bfloat16 Bsl[2][64 * 32];

    GemmP p;
    int bid;
    if ((int)blockIdx.x < p0.nblocks) { p = p0; bid = blockIdx.x; }
    else { p = p1; bid = (int)blockIdx.x - p0.nblocks; }

    int mt, nt;
    if (!p.swz) { mt = bid / p.ntiles; nt = bid % p.ntiles; }
    else {
        int g = bid / (8 * p.ntiles);
        int rem = bid % (8 * p.ntiles);
        mt = g * 8 + (rem & 7);
        nt = rem >> 3;
    }
    const int m0 = mt * 128;
    const int n0 = nt * 64;
    const int K = p.K;
    const int N = p.N;

    const int tid = threadIdx.x;
    const int lane = tid & 63;
    const int wv = tid >> 6;
    const int wm = wv >> 1;
    const int wn = wv & 1;
    const int col = lane & 15;
    const int quad = lane >> 4;

    const int srow = lane >> 2;
    const int scol = (lane & 3) * 8;
    const __hip_bfloat16* Ag = p.A + (size_t)m0 * K;
    const __hip_bfloat16* Bg = p.BT + (size_t)n0 * K;

    f32x4 acc[4][2] = {};

    for (int k0 = 0; k0 < K; k0 += 64) {
#pragma unroll
        for (int h = 0; h < 2; ++h) {
            int arow = wv * 32 + h * 16 + srow;
#pragma unroll
            for (int kc = 0; kc < 2; ++kc)
                async16(Ag + (size_t)arow * K + k0 + kc * 32 + scol,
                        &Asl[kc][arow * 32 + scol]);
        }
        {
            int brow = wv * 16 + srow;
#pragma unroll
            for (int kc = 0; kc < 2; ++kc)
                async16(Bg + (size_t)brow * K + k0 + kc * 32 + scol,
                        &Bsl[kc][brow * 32 + scol]);
        }
        __syncthreads();

#pragma unroll
        for (int kc = 0; kc < 2; ++kc) {
            short8 af[4], bfr[2];
#pragma unroll
            for (int i = 0; i < 4; ++i)
                af[i] = *(const short8*)(&Asl[kc][(wm * 64 + i * 16 + col) * 32 + quad * 8]);
#pragma unroll
            for (int j = 0; j < 2; ++j)
                bfr[j] = *(const short8*)(&Bsl[kc][(wn * 32 + j * 16 + col) * 32 + quad * 8]);
#pragma unroll
            for (int am = 0; am < 4; ++am)
#pragma unroll
                for (int bn = 0; bn < 2; ++bn)
                    acc[am][bn] = __builtin_amdgcn_mfma_f32_16x16x32_bf16(af[am], bfr[bn], acc[am][bn], 0, 0, 0);
        }
        __syncthreads();
    }

    int cF = (p.cMode == 1) ? 1 : ((p.cMode == 2) ? 0 : flag[0]);
#pragma unroll
    for (int am = 0; am < 4; ++am)
#pragma unroll
        for (int bn = 0; bn < 2; ++bn)
#pragma unroll
            for (int r = 0; r < 4; ++r) {
                size_t ci = (size_t)(m0 + wm * 64 + am * 16 + quad * 4 + r) * N
                            + n0 + wn * 32 + bn * 16 + col;
                float v = acc[am][bn][r] * p.alpha;
                if (cF) ((float*)p.C)[ci] = v;
                else ((__hip_bfloat16*)p.C)[ci] = __float2bfloat16(v);
            }
}

// ---------------------------------------------------------------------------
// Combine kvp_red [1536][128] fp32 -> SWIZZLED bf16 K/V tile images.
//
// Kb: 24 tiles of 8KB, tile g = keys [g*64, g*64+64). Within tile:
//   byte(key,d) = r*128 + ((slot ^ (r&7))<<4) + ((d&7)<<1),
//   r = key&63, slot = d>>3.   (slot^=(r&7) kills the 16-way ds_read conflict)
// Vt: 24 tiles of 8KB, tile g. Within tile:
//   byte(d,key) = d*128 + ((slotp ^ (d&7))<<4) + ((p&7)<<1),
//   p = R8 perm ((i&15)<<2)|(i>>4), i = key&63, slotp = p>>3.
// Tiles are contiguous 8KB -> attn stages them as pure linear copies via
// global_load_lds (rule #21: linear dest + pre-swizzled source + swz read).
// ---------------------------------------------------------------------------
__global__ __launch_bounds__(256) void sums_kernel(const float* __restrict__ kvp_red,
                                                   char* __restrict__ Kb,
                                                   char* __restrict__ Vt) {
    int t = blockIdx.x * 256 + threadIdx.x;
    int d = t & 63;
    int y = t >> 6;

    float kc = kvp_red[(size_t)y * 128 + d];
    float kf = kvp_red[(size_t)(512 + y) * 128 + d];
    float kl = kvp_red[(size_t)(1024 + y) * 128 + d];
    float vc = kvp_red[(size_t)y * 128 + 64 + d];
    float vf = kvp_red[(size_t)(512 + y) * 128 + 64 + d];
    float vl = kvp_red[(size_t)(1024 + y) * 128 + 64 + d];

    float kvals[3] = {kc - kl, kc, kc - kf};
    float vvals[3] = {vc - vl, vc, vc - vf};
#pragma unroll
    for (int e = 0; e < 3; ++e) {
        int key = e * W_ + y;
        int g = key >> 6;
        int r = key & 63;
        // K: row = key-in-tile, element d
        int kbyte = g * 8192 + r * 128 + ((((d >> 3) ^ (r & 7)) << 4)) + ((d & 7) << 1);
        *(__hip_bfloat16*)(Kb + kbyte) = __float2bfloat16(kvals[e]);
        // V: row = d, column = permuted key-in-tile
        int p = ((r & 15) << 2) | (r >> 4);
        int vbyte = g * 8192 + d * 128 + ((((p >> 3) ^ (d & 7)) << 4)) + ((p & 7) << 1);
        *(__hip_bfloat16*)(Vt + vbyte) = __float2bfloat16(vvals[e]);
    }
}

// ---------------------------------------------------------------------------
// Flash MFMA attention — Round 3: q-row-split (16 rows/wave, all 1536 keys)
// with COOPERATIVE LDS staging of K/V tiles. Fixes R2's 4x load amplification:
// all 4 waves consume the SAME 64-key tile each iter, so one 16KB stage (K+V,
// global_load_lds x16/thread-round) serves the whole block. Double-buffered,
// one barrier/iter (m97 2-phase). Global traffic/block back to 384KB (= R1).
// K/V fragment ds_reads use the producer-baked XOR swizzle (slot ^= row&7) ->
// conflict-free. P path, epilogue, indexing identical to R2 (which passed).
// LDS 41984B -> 3 blocks/CU. T5 setprio kept around MFMA clusters.
// ---------------------------------------------------------------------------
#define PSTRIDE 72
__global__ __launch_bounds__(256, 3) void attn_kernel(const __hip_bfloat16* __restrict__ qb,
                                                      const __hip_bfloat16* __restrict__ Kb,
                                                      const __hip_bfloat16* __restrict__ Vt,
                                                      __hip_bfloat16* __restrict__ ctx) {
    __shared__ __align__(16) __hip_bfloat16 Kbuf[2][4096];   // 2 x 8KB
    __shared__ __align__(16) __hip_bfloat16 Vbuf[2][4096];   // 2 x 8KB
    __shared__ __align__(16) __hip_bfloat16 psm[4][16 * PSTRIDE];

    const int tid = threadIdx.x;
    const int lane = tid & 63;
    const int wv = tid >> 6;
    const int m0 = blockIdx.x * 64 + wv * 16;   // this wave's 16 q-rows
    const int col = lane & 15;
    const int quad = lane >> 4;
    __hip_bfloat16* pw = psm[wv];

    const char* Kg = (const char*)Kb;
    const char* Vg = (const char*)Vt;
    const int so = tid * 16;                    // staging byte offset (linear)

    // read-swizzle byte offsets within a 128B row (slot ^ (row&7), row&7==col&7)
    const int off0 = ((quad ^ (col & 7)) << 4);
    const int off1 = (((quad + 4) ^ (col & 7)) << 4);

    short8 qf0, qf1;
    {
        const __hip_bfloat16* qp = qb + (size_t)(m0 + col) * 64 + quad * 8;
        qf0 = *(const short8*)(qp);
        qf1 = *(const short8*)(qp + 32);
    }

    f32x4 O[4] = {};
    float lrow[4] = {};

    // Prologue: stage tile 0 into buffer 0.
    async16(Kg + so, (char*)Kbuf[0] + so);
    async16(Kg + 4096 + so, (char*)Kbuf[0] + 4096 + so);
    async16(Vg + so, (char*)Vbuf[0] + so);
    async16(Vg + 4096 + so, (char*)Vbuf[0] + 4096 + so);
    __syncthreads();   // drains vmcnt -> tile 0 ready

    for (int t = 0; t < 24; ++t) {
        const int cur = t & 1;
        if (t < 23) {   // prefetch next tile into the other buffer
            const char* ks = Kg + (size_t)(t + 1) * 8192;
            const char* vs = Vg + (size_t)(t + 1) * 8192;
            char* kd = (char*)Kbuf[cur ^ 1];
            char* vd = (char*)Vbuf[cur ^ 1];
            async16(ks + so, kd + so);
            async16(ks + 4096 + so, kd + 4096 + so);
            async16(vs + so, vd + so);
            async16(vs + 4096 + so, vd + 4096 + so);
        }
        const char* Kc = (const char*)Kbuf[cur];
        const char* Vc = (const char*)Vbuf[cur];

        short8 kb0[4], kb1[4];
#pragma unroll
        for (int f = 0; f < 4; ++f) {
            const int rb = (f * 16 + col) * 128;
            kb0[f] = *(const short8*)(Kc + rb + off0);
            kb1[f] = *(const short8*)(Kc + rb + off1);
        }

        f32x4 S[4];
        __builtin_amdgcn_s_setprio(1);
#pragma unroll
        for (int f = 0; f < 4; ++f) {
            f32x4 s = {};
            s = __builtin_amdgcn_mfma_f32_16x16x32_bf16(qf0, kb0[f], s, 0, 0, 0);
            s = __builtin_amdgcn_mfma_f32_16x16x32_bf16(qf1, kb1[f], s, 0, 0, 0);
            S[f] = s;
        }
        __builtin_amdgcn_s_setprio(0);
#pragma unroll
        for (int f = 0; f < 4; ++f)
#pragma unroll
            for (int r = 0; r < 4; ++r) S[f][r] = FEXP2(S[f][r]);
#pragma unroll
        for (int r = 0; r < 4; ++r)
            lrow[r] += (S[0][r] + S[1][r]) + (S[2][r] + S[3][r]);
#pragma unroll
        for (int r = 0; r < 4; ++r) {
            __hip_bfloat162 p01 = __float22bfloat162_rn({S[0][r], S[1][r]});
            __hip_bfloat162 p23 = __float22bfloat162_rn({S[2][r], S[3][r]});
            short4 t4;
            *(__hip_bfloat162*)(&t4.x) = p01;
            *(__hip_bfloat162*)(&t4.z) = p23;
            *(short4*)(pw + (quad * 4 + r) * PSTRIDE + col * 4) = t4;
        }

        short8 vb0[4], vb1[4];
#pragma unroll
        for (int f = 0; f < 4; ++f) {
            const int rb = (f * 16 + col) * 128;
            vb0[f] = *(const short8*)(Vc + rb + off0);
            vb1[f] = *(const short8*)(Vc + rb + off1);
        }

        short8 a0 = *(const short8*)(pw + col * PSTRIDE + quad * 8);
        short8 a1 = *(const short8*)(pw + col * PSTRIDE + 32 + quad * 8);
        __builtin_amdgcn_s_setprio(1);
#pragma unroll
        for (int f = 0; f < 4; ++f) {
            O[f] = __builtin_amdgcn_mfma_f32_16x16x32_bf16(a0, vb0[f], O[f], 0, 0, 0);
            O[f] = __builtin_amdgcn_mfma_f32_16x16x32_bf16(a1, vb1[f], O[f], 0, 0, 0);
        }
        __builtin_amdgcn_s_setprio(0);

        __syncthreads();   // next-tile stage complete; all reads of cur done
    }

    // Sum lrow across the 16 cols of each quad-group (keys mod 16).
#pragma unroll
    for (int msk = 1; msk <= 8; msk <<= 1)
#pragma unroll
        for (int r = 0; r < 4; ++r) lrow[r] += __shfl_xor(lrow[r], msk, 64);

    // Direct epilogue: O[f][r] is ctx[row = m0 + quad*4 + r][dh = f*16 + col].
#pragma unroll
    for (int r = 0; r < 4; ++r) {
        float inv = 1.f / lrow[r];
#pragma unroll
        for (int f = 0; f < 4; ++f)
            ctx[(size_t)(m0 + quad * 4 + r) * 64 + f * 16 + col] =
                __float2bfloat16(O[f][r] * inv);
    }
}

// ---------------------------------------------------------------------------
// Launch
// ---------------------------------------------------------------------------
extern "C" void kernel_launch(void* const* d_in, const int* in_sizes, int n_in,
                              void* d_out, int out_size, void* d_ws, size_t ws_size,
                              hipStream_t stream) {
    const void* q   = d_in[0];
    const void* kv  = d_in[1];
    const void* Wq  = d_in[2];
    const void* Wkv = d_in[3];
    const void* Wc  = d_in[4];

    char* ws = (char*)d_ws;
    size_t off = 0;
    int* flag = (int*)(ws + off); off += 1024;
    __hip_bfloat16* qbuf   = (__hip_bfloat16*)(ws + off); off += (size_t)L_ * DM_ * 2;     // 8 MB
    __hip_bfloat16* WqT    = (__hip_bfloat16*)(ws + off); off += (size_t)DM_ * DM_ * 2;    // 2 MB
    __hip_bfloat16* WkvT   = (__hip_bfloat16*)(ws + off); off += (size_t)128 * DM_ * 2;    // 256 KB
    __hip_bfloat16* WcT    = (__hip_bfloat16*)(ws + off); off += (size_t)DM_ * DM_ * 2;    // 2 MB
    __hip_bfloat16* qb     = (__hip_bfloat16*)(ws + off); off += (size_t)L_ * DM_ * 2;     // 8 MB
    __hip_bfloat16* kvred  = (__hip_bfloat16*)(ws + off); off += (size_t)1536 * 1024 * 2;  // 3 MB
    float*          kvpred = (float*)(ws + off);          off += (size_t)1536 * 128 * 4;   // 768 KB
    __hip_bfloat16* Kb     = (__hip_bfloat16*)(ws + off); off += (size_t)W3_ * 64 * 2;     // 192 KB
    __hip_bfloat16* Vt     = (__hip_bfloat16*)(ws + off); off += (size_t)64 * W3_ * 2;     // 192 KB
    __hip_bfloat16* ctxb   = (__hip_bfloat16*)(ws + off);                                  // 8 MB

    detect_kernel<<<1, 256, 0, stream>>>((const uint4*)q, flag);

    megaprep<<<6176, 256, 0, stream>>>(q, kv, Wq, Wkv, Wc,
                                       qbuf, WqT, WkvT, WcT, kvred, flag);

    // Merged dispatch: qb = (q @ Wq) * (1/8)*log2(e), bf16 (512 blocks) PLUS
    // kvp_red = kvred @ Wkv, fp32 (24 blocks riding on idle CUs).
    {
        GemmP pq{qbuf, WqT, (void*)qb, L_, DM_, DM_,
                 0.125f * 1.44269504f, 2, 16, 1, 512};
        GemmP pk{kvred, WkvT, (void*)kvpred, 1536, 128, DM_,
                 1.0f, 1, 2, 0, 24};
        gemm_bt_mfma<<<536, 256, 0, stream>>>(pq, pk, flag);
    }
    sums_kernel<<<128, 256, 0, stream>>>(kvpred, (char*)Kb, (char*)Vt);
    attn_kernel<<<dim3(NROWS_ / 64), 256, 0, stream>>>(qb, Kb, Vt, ctxb);
    // out = ctx @ Wc, dtype per flag
    {
        GemmP pc{ctxb, WcT, d_out, L_, DM_, DM_, 1.0f, 0, 16, 1, 512};
        GemmP pnull{};
        pnull.nblocks = 0;
        gemm_bt_mfma<<<512, 256, 0, stream>>>(pc, pnull, flag);
    }
}

// Round 4
// 182.229 us; speedup vs baseline: 1.7328x; 1.0341x over previous
//
#include <hip/hip_runtime.h>
#include <hip/hip_bf16.h>
#include <cstdint>
#include <cstddef>

// Problem constants: B=1, L=4096, DM=1024, NH=16, DH=64, w=512, C=8
#define L_ 4096
#define DM_ 1024
#define NH_ 16
#define DH_ 64
#define W_ 512
#define C_ 8
#define W3_ 1536
#define NROWS_ 65536

typedef __attribute__((ext_vector_type(8))) short short8;
typedef __attribute__((ext_vector_type(4))) float f32x4;

__device__ __forceinline__ void async16(const void* g, void* l) {
    __builtin_amdgcn_global_load_lds(
        (const __attribute__((address_space(1))) unsigned int*)g,
        (__attribute__((address_space(3))) unsigned int*)l, 16, 0, 0);
}

#if __has_builtin(__builtin_amdgcn_exp2f)
#define FEXP2(x) __builtin_amdgcn_exp2f(x)
#else
#define FEXP2(x) exp2f(x)
#endif

__device__ __forceinline__ int nanhit(unsigned u) {
    return (((u & 0x7F80u) == 0x7F80u) | (((u >> 16) & 0x7F80u) == 0x7F80u));
}

__device__ __forceinline__ float ldf(const void* X, size_t i, int f32) {
    return f32 ? ((const float*)X)[i] : __bfloat162float(((const __hip_bfloat16*)X)[i]);
}

// ---------------------------------------------------------------------------
// Megaprep (one dispatch, detect folded in): each block self-detects dtype
// from the first 16KB of q (L2-hot; P(false-bf16) ~ e^-16), block 0 publishes
// flag for the final GEMM.
//   blocks    0..4095: q convert -> qbuf bf16
//   blocks 4096..4639: Wq^T (256), Wc^T (256), Wkv^T (32)
//   blocks 4640..5151: kvcomb build (512, one per y):
//     row       y = chunks 0..6 sum   (-> K/V edge e=0 after GEMM)
//     row  512+ y = chunks 0..7 sum   (e=1)
//     row 1024+ y = chunks 1..7 sum   (e=2)
//   (linearity: combining BEFORE the Wkv GEMM lets the GEMM output the final
//    K/V values directly, deleting the sums_kernel dispatch)
// ---------------------------------------------------------------------------
__global__ __launch_bounds__(256) void megaprep(const void* __restrict__ q,
                                                const void* __restrict__ kv,
                                                const void* __restrict__ Wq,
                                                const void* __restrict__ Wkv,
                                                const void* __restrict__ Wc,
                                                __hip_bfloat16* __restrict__ qbuf,
                                                __hip_bfloat16* __restrict__ WqT,
                                                __hip_bfloat16* __restrict__ WkvT,
                                                __hip_bfloat16* __restrict__ WcT,
                                                __hip_bfloat16* __restrict__ kvcomb,
                                                int* __restrict__ flag) {
    __shared__ float t[64][65];
    __shared__ int sflag;
    const int b = blockIdx.x;
    const int tid = threadIdx.x;

    // --- self-detect dtype (fp32 -> low-half mantissa bits trip nanhit) ---
    if (tid == 0) sflag = 0;
    __syncthreads();
    {
        int hit = 0;
#pragma unroll
        for (int r = 0; r < 4; ++r) {
            uint4 v = ((const uint4*)q)[tid + 256 * r];
            hit |= nanhit(v.x) | nanhit(v.y) | nanhit(v.z) | nanhit(v.w);
        }
        if (__any(hit)) { if ((tid & 63) == 0) atomicOr(&sflag, 1); }
    }
    __syncthreads();
    const int f32 = sflag;
    if (b == 0 && tid == 0) flag[0] = f32;   // consumed by the final GEMM

    if (b < 4096) {
        int i = (b * 256 + tid) * 4;
        if (f32) {
            float4 v = *(const float4*)((const float*)q + i);
            __hip_bfloat162 tmp[2] = {__float22bfloat162_rn({v.x, v.y}),
                                      __float22bfloat162_rn({v.z, v.w})};
            *(short4*)((short*)qbuf + i) = *(const short4*)tmp;
        } else {
            *(short4*)((short*)qbuf + i) = *(const short4*)((const short*)q + i);
        }
    } else if (b < 4640) {
        const void* W;
        __hip_bfloat16* WT;
        int K = 1024, N, n0, k0;
        if (b < 4352) {
            int bx = b - 4096; W = Wq; WT = WqT; N = 1024;
            n0 = (bx & 15) * 64; k0 = (bx >> 4) * 64;
        } else if (b < 4608) {
            int bx = b - 4352; W = Wc; WT = WcT; N = 1024;
            n0 = (bx & 15) * 64; k0 = (bx >> 4) * 64;
        } else {
            int bx = b - 4608; W = Wkv; WT = WkvT; N = 128;
            n0 = (bx & 1) * 64; k0 = (bx >> 1) * 64;
        }
        const int tx = tid & 63;
        const int ty = tid >> 6;
#pragma unroll
        for (int r = 0; r < 16; ++r) {
            int k = ty + r * 4;
            t[k][tx] = ldf(W, (size_t)(k0 + k) * N + n0 + tx, f32);
        }
        __syncthreads();
#pragma unroll
        for (int r = 0; r < 16; ++r) {
            int n = ty + r * 4;
            WT[(size_t)(n0 + n) * K + k0 + tx] = __float2bfloat16(t[tx][n]);
        }
    } else {
        int y = b - 4640;           // 0..511
        int c = tid * 4;
        float s0 = 0, s1 = 0, s2 = 0, s3 = 0;
        float f0 = 0, f1 = 0, f2 = 0, f3 = 0;
        float l0 = 0, l1 = 0, l2 = 0, l3 = 0;
#pragma unroll
        for (int z = 0; z < C_; ++z) {
            size_t base = (size_t)(z * W_ + y) * 1024 + c;
            float a0, a1, a2, a3;
            if (f32) {
                float4 v = *(const float4*)((const float*)kv + base);
                a0 = v.x; a1 = v.y; a2 = v.z; a3 = v.w;
            } else {
                short4 v = *(const short4*)((const short*)kv + base);
                a0 = __bfloat162float(*(__hip_bfloat16*)&v.x);
                a1 = __bfloat162float(*(__hip_bfloat16*)&v.y);
                a2 = __bfloat162float(*(__hip_bfloat16*)&v.z);
                a3 = __bfloat162float(*(__hip_bfloat16*)&v.w);
            }
            s0 += a0; s1 += a1; s2 += a2; s3 += a3;
            if (z == 0) { f0 = a0; f1 = a1; f2 = a2; f3 = a3; }
            if (z == C_ - 1) { l0 = a0; l1 = a1; l2 = a2; l3 = a3; }
        }
        auto store = [&](int row, float x0, float x1, float x2, float x3) {
            __hip_bfloat162 tmp[2] = {__float22bfloat162_rn({x0, x1}),
                                      __float22bfloat162_rn({x2, x3})};
            *(short4*)((short*)kvcomb + (size_t)row * 1024 + c) = *(const short4*)tmp;
        };
        store(y,        s0 - l0, s1 - l1, s2 - l2, s3 - l3);
        store(512 + y,  s0, s1, s2, s3);
        store(1024 + y, s0 - f0, s1 - f1, s2 - f2, s3 - f3);
    }
}

// ---------------------------------------------------------------------------
// MFMA GEMM: C[M,N] = alpha * A[M,K] @ BT[N,K]^T, bf16 in, fp32 accum.
// 128x64 tile, BK=64 (two BK=32 sub-tiles). swz=1: XCD swizzle mapping.
// cMode: 0 = follow flag (fp32 if flag else bf16), 1 = fp32, 2 = bf16,
//        3 = K/V epilogue: rows are keys (0..1535), cols 0..63 -> Kb swizzled
//            tiles, cols 64..127 -> Vt swizzled+R8-permuted tiles (formulas
//            identical to the old sums_kernel; C = Kb, C2 = Vt).
// Dual-problem dispatch: blocks [0, p0.nblocks) run p0, the rest run p1.
// ---------------------------------------------------------------------------
struct GemmP {
    const __hip_bfloat16* A;
    const __hip_bfloat16* BT;
    void* C;
    int M, N, K;
    float alpha;
    int cMode;
    int ntiles;   // N / 64
    int swz;
    int nblocks;
    void* C2;
};

__global__ __launch_bounds__(256) void gemm_bt_mfma(GemmP p0, GemmP p1,
                                                    const int* __restrict__ flag) {
    __shared__ __hip_bfloat16 Asl[2][128 * 32];
    __shared__ __hip_bfloat16 Bsl[2][64 * 32];

    GemmP p;
    int bid;
    if ((int)blockIdx.x < p0.nblocks) { p = p0; bid = blockIdx.x; }
    else { p = p1; bid = (int)blockIdx.x - p0.nblocks; }

    int mt, nt;
    if (!p.swz) { mt = bid / p.ntiles; nt = bid % p.ntiles; }
    else {
        int g = bid / (8 * p.ntiles);
        int rem = bid % (8 * p.ntiles);
        mt = g * 8 + (rem & 7);
        nt = rem >> 3;
    }
    const int m0 = mt * 128;
    const int n0 = nt * 64;
    const int K = p.K;
    const int N = p.N;

    const int tid = threadIdx.x;
    const int lane = tid & 63;
    const int wv = tid >> 6;
    const int wm = wv >> 1;
    const int wn = wv & 1;
    const int col = lane & 15;
    const int quad = lane >> 4;

    const int srow = lane >> 2;
    const int scol = (lane & 3) * 8;
    const __hip_bfloat16* Ag = p.A + (size_t)m0 * K;
    const __hip_bfloat16* Bg = p.BT + (size_t)n0 * K;

    f32x4 acc[4][2] = {};

    for (int k0 = 0; k0 < K; k0 += 64) {
#pragma unroll
        for (int h = 0; h < 2; ++h) {
            int arow = wv * 32 + h * 16 + srow;
#pragma unroll
            for (int kc = 0; kc < 2; ++kc)
                async16(Ag + (size_t)arow * K + k0 + kc * 32 + scol,
                        &Asl[kc][arow * 32 + scol]);
        }
        {
            int brow = wv * 16 + srow;
#pragma unroll
            for (int kc = 0; kc < 2; ++kc)
                async16(Bg + (size_t)brow * K + k0 + kc * 32 + scol,
                        &Bsl[kc][brow * 32 + scol]);
        }
        __syncthreads();

#pragma unroll
        for (int kc = 0; kc < 2; ++kc) {
            short8 af[4], bfr[2];
#pragma unroll
            for (int i = 0; i < 4; ++i)
                af[i] = *(const short8*)(&Asl[kc][(wm * 64 + i * 16 + col) * 32 + quad * 8]);
#pragma unroll
            for (int j = 0; j < 2; ++j)
                bfr[j] = *(const short8*)(&Bsl[kc][(wn * 32 + j * 16 + col) * 32 + quad * 8]);
#pragma unroll
            for (int am = 0; am < 4; ++am)
#pragma unroll
                for (int bn = 0; bn < 2; ++bn)
                    acc[am][bn] = __builtin_amdgcn_mfma_f32_16x16x32_bf16(af[am], bfr[bn], acc[am][bn], 0, 0, 0);
        }
        __syncthreads();
    }

    if (p.cMode == 3) {
        // K/V epilogue: scatter bf16 into swizzled tile images.
#pragma unroll
        for (int am = 0; am < 4; ++am)
#pragma unroll
            for (int bn = 0; bn < 2; ++bn)
#pragma unroll
                for (int r = 0; r < 4; ++r) {
                    int key = m0 + wm * 64 + am * 16 + quad * 4 + r;
                    int c = n0 + wn * 32 + bn * 16 + col;
                    float v = acc[am][bn][r];
                    int g = key >> 6, kr = key & 63;
                    if (c < 64) {
                        int byt = g * 8192 + kr * 128 +
                                  ((((c >> 3) ^ (kr & 7)) << 4)) + ((c & 7) << 1);
                        *(__hip_bfloat16*)((char*)p.C + byt) = __float2bfloat16(v);
                    } else {
                        int d = c - 64;
                        int pp = ((kr & 15) << 2) | (kr >> 4);
                        int byt = g * 8192 + d * 128 +
                                  ((((pp >> 3) ^ (d & 7)) << 4)) + ((pp & 7) << 1);
                        *(__hip_bfloat16*)((char*)p.C2 + byt) = __float2bfloat16(v);
                    }
                }
        return;
    }

    int cF = (p.cMode == 1) ? 1 : ((p.cMode == 2) ? 0 : flag[0]);
#pragma unroll
    for (int am = 0; am < 4; ++am)
#pragma unroll
        for (int bn = 0; bn < 2; ++bn)
#pragma unroll
            for (int r = 0; r < 4; ++r) {
                size_t ci = (size_t)(m0 + wm * 64 + am * 16 + quad * 4 + r) * N
                            + n0 + wn * 32 + bn * 16 + col;
                float v = acc[am][bn][r] * p.alpha;
                if (cF) ((float*)p.C)[ci] = v;
                else ((__hip_bfloat16*)p.C)[ci] = __float2bfloat16(v);
            }
}

// ---------------------------------------------------------------------------
// Flash MFMA attention — unchanged from Round 3 (passed, 57 µs): q-row-split
// (16 rows/wave, all 1536 keys), cooperative double-buffered LDS staging of
// swizzled K/V tiles via global_load_lds, conflict-free swizzled ds_reads,
// wave-private P LDS, T5 setprio. LDS 41984B, VGPR 68.
// ---------------------------------------------------------------------------
#define PSTRIDE 72
__global__ __launch_bounds__(256, 3) void attn_kernel(const __hip_bfloat16* __restrict__ qb,
                                                      const __hip_bfloat16* __restrict__ Kb,
                                                      const __hip_bfloat16* __restrict__ Vt,
                                                      __hip_bfloat16* __restrict__ ctx) {
    __shared__ __align__(16) __hip_bfloat16 Kbuf[2][4096];   // 2 x 8KB
    __shared__ __align__(16) __hip_bfloat16 Vbuf[2][4096];   // 2 x 8KB
    __shared__ __align__(16) __hip_bfloat16 psm[4][16 * PSTRIDE];

    const int tid = threadIdx.x;
    const int lane = tid & 63;
    const int wv = tid >> 6;
    const int m0 = blockIdx.x * 64 + wv * 16;   // this wave's 16 q-rows
    const int col = lane & 15;
    const int quad = lane >> 4;
    __hip_bfloat16* pw = psm[wv];

    const char* Kg = (const char*)Kb;
    const char* Vg = (const char*)Vt;
    const int so = tid * 16;                    // staging byte offset (linear)

    // read-swizzle byte offsets within a 128B row (slot ^ (row&7), row&7==col&7)
    const int off0 = ((quad ^ (col & 7)) << 4);
    const int off1 = (((quad + 4) ^ (col & 7)) << 4);

    short8 qf0, qf1;
    {
        const __hip_bfloat16* qp = qb + (size_t)(m0 + col) * 64 + quad * 8;
        qf0 = *(const short8*)(qp);
        qf1 = *(const short8*)(qp + 32);
    }

    f32x4 O[4] = {};
    float lrow[4] = {};

    // Prologue: stage tile 0 into buffer 0.
    async16(Kg + so, (char*)Kbuf[0] + so);
    async16(Kg + 4096 + so, (char*)Kbuf[0] + 4096 + so);
    async16(Vg + so, (char*)Vbuf[0] + so);
    async16(Vg + 4096 + so, (char*)Vbuf[0] + 4096 + so);
    __syncthreads();   // drains vmcnt -> tile 0 ready

    for (int t = 0; t < 24; ++t) {
        const int cur = t & 1;
        if (t < 23) {   // prefetch next tile into the other buffer
            const char* ks = Kg + (size_t)(t + 1) * 8192;
            const char* vs = Vg + (size_t)(t + 1) * 8192;
            char* kd = (char*)Kbuf[cur ^ 1];
            char* vd = (char*)Vbuf[cur ^ 1];
            async16(ks + so, kd + so);
            async16(ks + 4096 + so, kd + 4096 + so);
            async16(vs + so, vd + so);
            async16(vs + 4096 + so, vd + 4096 + so);
        }
        const char* Kc = (const char*)Kbuf[cur];
        const char* Vc = (const char*)Vbuf[cur];

        short8 kb0[4], kb1[4];
#pragma unroll
        for (int f = 0; f < 4; ++f) {
            const int rb = (f * 16 + col) * 128;
            kb0[f] = *(const short8*)(Kc + rb + off0);
            kb1[f] = *(const short8*)(Kc + rb + off1);
        }

        f32x4 S[4];
        __builtin_amdgcn_s_setprio(1);
#pragma unroll
        for (int f = 0; f < 4; ++f) {
            f32x4 s = {};
            s = __builtin_amdgcn_mfma_f32_16x16x32_bf16(qf0, kb0[f], s, 0, 0, 0);
            s = __builtin_amdgcn_mfma_f32_16x16x32_bf16(qf1, kb1[f], s, 0, 0, 0);
            S[f] = s;
        }
        __builtin_amdgcn_s_setprio(0);
#pragma unroll
        for (int f = 0; f < 4; ++f)
#pragma unroll
            for (int r = 0; r < 4; ++r) S[f][r] = FEXP2(S[f][r]);
#pragma unroll
        for (int r = 0; r < 4; ++r)
            lrow[r] += (S[0][r] + S[1][r]) + (S[2][r] + S[3][r]);
#pragma unroll
        for (int r = 0; r < 4; ++r) {
            __hip_bfloat162 p01 = __float22bfloat162_rn({S[0][r], S[1][r]});
            __hip_bfloat162 p23 = __float22bfloat162_rn({S[2][r], S[3][r]});
            short4 t4;
            *(__hip_bfloat162*)(&t4.x) = p01;
            *(__hip_bfloat162*)(&t4.z) = p23;
            *(short4*)(pw + (quad * 4 + r) * PSTRIDE + col * 4) = t4;
        }

        short8 vb0[4], vb1[4];
#pragma unroll
        for (int f = 0; f < 4; ++f) {
            const int rb = (f * 16 + col) * 128;
            vb0[f] = *(const short8*)(Vc + rb + off0);
            vb1[f] = *(const short8*)(Vc + rb + off1);
        }

        short8 a0 = *(const short8*)(pw + col * PSTRIDE + quad * 8);
        short8 a1 = *(const short8*)(pw + col * PSTRIDE + 32 + quad * 8);
        __builtin_amdgcn_s_setprio(1);
#pragma unroll
        for (int f = 0; f < 4; ++f) {
            O[f] = __builtin_amdgcn_mfma_f32_16x16x32_bf16(a0, vb0[f], O[f], 0, 0, 0);
            O[f] = __builtin_amdgcn_mfma_f32_16x16x32_bf16(a1, vb1[f], O[f], 0, 0, 0);
        }
        __builtin_amdgcn_s_setprio(0);

        __syncthreads();   // next-tile stage complete; all reads of cur done
    }

    // Sum lrow across the 16 cols of each quad-group (keys mod 16).
#pragma unroll
    for (int msk = 1; msk <= 8; msk <<= 1)
#pragma unroll
        for (int r = 0; r < 4; ++r) lrow[r] += __shfl_xor(lrow[r], msk, 64);

    // Direct epilogue: O[f][r] is ctx[row = m0 + quad*4 + r][dh = f*16 + col].
#pragma unroll
    for (int r = 0; r < 4; ++r) {
        float inv = 1.f / lrow[r];
#pragma unroll
        for (int f = 0; f < 4; ++f)
            ctx[(size_t)(m0 + quad * 4 + r) * 64 + f * 16 + col] =
                __float2bfloat16(O[f][r] * inv);
    }
}

// ---------------------------------------------------------------------------
// Launch: 4 dispatches (was 6) — megaprep -> merged GEMM (qb + K/V direct)
// -> attn -> out GEMM.
// ---------------------------------------------------------------------------
extern "C" void kernel_launch(void* const* d_in, const int* in_sizes, int n_in,
                              void* d_out, int out_size, void* d_ws, size_t ws_size,
                              hipStream_t stream) {
    const void* q   = d_in[0];
    const void* kv  = d_in[1];
    const void* Wq  = d_in[2];
    const void* Wkv = d_in[3];
    const void* Wc  = d_in[4];

    char* ws = (char*)d_ws;
    size_t off = 0;
    int* flag = (int*)(ws + off); off += 1024;
    __hip_bfloat16* qbuf   = (__hip_bfloat16*)(ws + off); off += (size_t)L_ * DM_ * 2;     // 8 MB
    __hip_bfloat16* WqT    = (__hip_bfloat16*)(ws + off); off += (size_t)DM_ * DM_ * 2;    // 2 MB
    __hip_bfloat16* WkvT   = (__hip_bfloat16*)(ws + off); off += (size_t)128 * DM_ * 2;    // 256 KB
    __hip_bfloat16* WcT    = (__hip_bfloat16*)(ws + off); off += (size_t)DM_ * DM_ * 2;    // 2 MB
    __hip_bfloat16* qb     = (__hip_bfloat16*)(ws + off); off += (size_t)L_ * DM_ * 2;     // 8 MB
    __hip_bfloat16* kvcomb = (__hip_bfloat16*)(ws + off); off += (size_t)1536 * 1024 * 2;  // 3 MB
    __hip_bfloat16* Kb     = (__hip_bfloat16*)(ws + off); off += (size_t)W3_ * 64 * 2;     // 192 KB
    __hip_bfloat16* Vt     = (__hip_bfloat16*)(ws + off); off += (size_t)64 * W3_ * 2;     // 192 KB
    __hip_bfloat16* ctxb   = (__hip_bfloat16*)(ws + off);                                  // 8 MB

    megaprep<<<5152, 256, 0, stream>>>(q, kv, Wq, Wkv, Wc,
                                       qbuf, WqT, WkvT, WcT, kvcomb, flag);

    // Merged dispatch: qb = (q @ Wq) * (1/8)*log2(e), bf16 (512 blocks) PLUS
    // {Kb,Vt} = kvcomb @ Wkv with swizzled K/V epilogue (24 blocks).
    {
        GemmP pq{qbuf, WqT, (void*)qb, L_, DM_, DM_,
                 0.125f * 1.44269504f, 2, 16, 1, 512, nullptr};
        GemmP pk{kvcomb, WkvT, (void*)Kb, 1536, 128, DM_,
                 1.0f, 3, 2, 0, 24, (void*)Vt};
        gemm_bt_mfma<<<536, 256, 0, stream>>>(pq, pk, flag);
    }
    attn_kernel<<<dim3(NROWS_ / 64), 256, 0, stream>>>(qb, Kb, Vt, ctxb);
    // out = ctx @ Wc, dtype per flag
    {
        GemmP pc{ctxb, WcT, d_out, L_, DM_, DM_, 1.0f, 0, 16, 1, 512, nullptr};
        GemmP pnull{};
        pnull.nblocks = 0;
        gemm_bt_mfma<<<512, 256, 0, stream>>>(pc, pnull, flag);
    }
}